// Round 7
// baseline (215.536 us; speedup 1.0000x reference)
//
#include <hip/hip_runtime.h>
#include <hip/hip_bf16.h>
#include <math.h>

// Problem constants: N=2, D=384, 2U=256, nH=8, hd=48, nL=4, nP=4
#define DM   384
#define U2   256
#define HD   48

typedef __attribute__((ext_vector_type(8))) short short8;   // 8 bf16 = 4 VGPR
typedef __attribute__((ext_vector_type(4))) float floatx4;  // MFMA acc
typedef __attribute__((ext_vector_type(2))) float floatx2;  // pk_fma pair

static __device__ __forceinline__ unsigned short f2bfbits(float f) {
    __hip_bfloat16 h = __float2bfloat16(f);
    return *reinterpret_cast<unsigned short*>(&h);
}
static __device__ __forceinline__ unsigned pack2(float x, float y) {
    return (unsigned)f2bfbits(x) | ((unsigned)f2bfbits(y) << 16);
}
static __device__ __forceinline__ float bflo(unsigned u) { return __uint_as_float(u << 16); }
static __device__ __forceinline__ float bfhi(unsigned u) { return __uint_as_float(u & 0xffff0000u); }

// =====================================================================
// Prep (R4-proven): query->bf16, flat->bf16 (vectorized) + 7 weight
// transposes. Separate bf16 cast pass AMORTIZES the A re-reads in
// GEMM1 — fusing the cast into GEMM1 regressed (R5).
// =====================================================================
struct PrepParams {
    const float* q; const float* f;
    __hip_bfloat16 *q_bf, *f_bf;
    const float* wsrc[7]; __hip_bfloat16* wdst[7];
    int K[7], N[7], off[8];
    int nQ4, nF4, total;
};
__global__ __launch_bounds__(256) void prep_kernel(PrepParams d) {
    const int idx = blockIdx.x * 256 + threadIdx.x;
    if (idx >= d.total) return;
    if (idx < d.nQ4) {
        const int i4 = idx * 4;
        const float4 v = *(const float4*)&d.q[i4];
        uint2 pk; pk.x = pack2(v.x, v.y); pk.y = pack2(v.z, v.w);
        *(uint2*)&d.q_bf[i4] = pk;
        return;
    }
    if (idx < d.nQ4 + d.nF4) {
        const int i4 = (idx - d.nQ4) * 4;
        const float4 v = *(const float4*)&d.f[i4];
        uint2 pk; pk.x = pack2(v.x, v.y); pk.y = pack2(v.z, v.w);
        *(uint2*)&d.f_bf[i4] = pk;
        return;
    }
    const int iw = idx - d.nQ4 - d.nF4;
    int s = 0;
#pragma unroll
    for (int i = 1; i < 7; ++i) if (iw >= d.off[i]) s = i;
    const int r = iw - d.off[s];
    const int k = r / d.N[s], n = r - k * d.N[s];
    d.wdst[s][(size_t)n * d.K[s] + k] = __float2bfloat16(d.wsrc[s][r]);
}

// =====================================================================
// Multi-segment MFMA GEMM v5: R0 skeleton (BK=32, register prefetch,
// 2-barrier loop) widened to a 64x128 output tile:
//  - 8 MFMAs per thread per K-step (was 4) — double per-barrier density
//  - same A staging; B staging 2 short8/thread; LDS 5+10=15KB (>=4 blk/CU)
//  - block count halves -> A re-reads and launches halve
//  - XCD y-grouping remap kept (R6-proven, same-bx blocks share one L2)
// omode: 0 = f32 out; 1 = bf16 out; 2/3 = bf16 scatter into combined
// value layout (top/bot): idx = row*768 + (col/48)*96 + (omode==3)*48 + col%48
// =====================================================================
struct Seg {
    const __hip_bfloat16* A; int lda;
    const __hip_bfloat16* Bt; int ldbt;
    const float* bias; void* C; int ldc; int K; int omode;
};
struct SegParams { Seg seg[5]; int ystart[5]; int nseg; int ny; };

__global__ __launch_bounds__(256) void gemm_seg_kernel(SegParams p) {
    __shared__ __hip_bfloat16 As[64 * 40];    //  5 KB
    __shared__ __hip_bfloat16 Bs[128 * 40];   // 10 KB

    // ---- XCD y-grouping remap (bijective chunked, m204 form) ----
    const int nb = gridDim.x;
    const int q8 = nb >> 3, r8 = nb & 7;
    const int c  = blockIdx.x & 7;
    const int i  = c * q8 + min(c, r8) + (blockIdx.x >> 3);
    const int bxi = i / p.ny;
    const int yb  = i - bxi * p.ny;

    int s = 0;
#pragma unroll
    for (int k = 1; k < 5; ++k) if (k < p.nseg && yb >= p.ystart[k]) s = k;
    Seg sg;
    switch (s) {
        case 0: sg = p.seg[0]; break;
        case 1: sg = p.seg[1]; break;
        case 2: sg = p.seg[2]; break;
        case 3: sg = p.seg[3]; break;
        default: sg = p.seg[4]; break;
    }
    const int by = yb - p.ystart[s];

    const int t    = threadIdx.x;
    const int bm   = bxi * 64;
    const int bn   = by * 128;
    const int w    = t >> 6, lane = t & 63;
    const int wm   = (w >> 1) * 32;          // rows  [wm, wm+32)
    const int wn   = (w & 1) * 64;           // cols  [wn, wn+64)
    const int quad = lane >> 4, lm = lane & 15;

    const int r0 = t >> 2, kc = (t & 3) * 8;

    const __hip_bfloat16* Ap  = sg.A  + (size_t)(bm + r0) * sg.lda  + kc;
    const __hip_bfloat16* Bp0 = sg.Bt + (size_t)(bn + r0) * sg.ldbt + kc;
    const __hip_bfloat16* Bp1 = Bp0 + (size_t)64 * sg.ldbt;

    short8 abf  = *(const short8*)Ap;
    short8 bbf0 = *(const short8*)Bp0;
    short8 bbf1 = *(const short8*)Bp1;

    floatx4 acc[2][4] = {};

    for (int k0 = 0; k0 < sg.K; k0 += 32) {
        *(short8*)&As[r0 * 40 + kc]        = abf;
        *(short8*)&Bs[r0 * 40 + kc]        = bbf0;
        *(short8*)&Bs[(r0 + 64) * 40 + kc] = bbf1;
        __syncthreads();

        const int kn = k0 + 32;
        if (kn < sg.K) {
            abf  = *(const short8*)(Ap + kn);
            bbf0 = *(const short8*)(Bp0 + kn);
            bbf1 = *(const short8*)(Bp1 + kn);
        }

        short8 af[2], bf[4];
#pragma unroll
        for (int ii = 0; ii < 2; ++ii)
            af[ii] = *(const short8*)&As[(wm + ii * 16 + lm) * 40 + quad * 8];
#pragma unroll
        for (int j = 0; j < 4; ++j)
            bf[j] = *(const short8*)&Bs[(wn + j * 16 + lm) * 40 + quad * 8];
#pragma unroll
        for (int ii = 0; ii < 2; ++ii)
#pragma unroll
            for (int j = 0; j < 4; ++j)
                acc[ii][j] = __builtin_amdgcn_mfma_f32_16x16x32_bf16(
                    af[ii], bf[j], acc[ii][j], 0, 0, 0);
        __syncthreads();
    }

#pragma unroll
    for (int ii = 0; ii < 2; ++ii)
#pragma unroll
        for (int reg = 0; reg < 4; ++reg) {
            const int row = bm + wm + ii * 16 + quad * 4 + reg;
#pragma unroll
            for (int j = 0; j < 4; ++j) {
                const int col = bn + wn + j * 16 + lm;
                const float v = acc[ii][j][reg] + sg.bias[col];
                if (sg.omode == 0) {
                    ((float*)sg.C)[(size_t)row * sg.ldc + col] = v;
                } else if (sg.omode == 1) {
                    ((__hip_bfloat16*)sg.C)[(size_t)row * sg.ldc + col] = __float2bfloat16(v);
                } else {
                    const int h = col / 48;
                    const size_t idx = (size_t)row * 768 + h * 96 +
                                       ((sg.omode == 3) ? 48 : 0) + (col - h * 48);
                    ((__hip_bfloat16*)sg.C)[idx] = __float2bfloat16(v);
                }
            }
        }
}

// =====================================================================
// Fused sampler v12 (exact R2 form — measured 56.8-57.4 us, 739K bank
// conflicts; near its random-gather L2 floor):
//  - batch-interleaved blockIdx mapping (XCD parity split)
//  - softmax on wave 2, concurrent with setup phase
// =====================================================================
#define SPP 524

__global__ __launch_bounds__(192) void sampler_kernel(
    const float* __restrict__ off_buf,    // (M, 256) fp32
    const float* __restrict__ logit_top,  // (M, 128)
    const float* __restrict__ logit_bot,  // (M, 128)
    const float* __restrict__ ref_pts,    // (M, 4, 2)
    const int*   __restrict__ ss,         // (4,2) [H,W]
    const int*   __restrict__ lsi,        // (4,)
    const __hip_bfloat16* __restrict__ vcomb,  // (Mv, 768) combined
    __hip_bfloat16* __restrict__ core_top,     // (M, 384) bf16
    __hip_bfloat16* __restrict__ core_bot,     // (M, 384) bf16
    int Lq, int LenIn)
{
    __shared__ float    sA[2][128];
    __shared__ unsigned sP[2][SPP];
    __shared__ float4   sRed[96][2];

    // batch-interleave: even bx -> batch 0, odd bx -> batch 1
    const int bx  = blockIdx.x;
    const int bid = (bx & 1) * Lq + (bx >> 1);
    const int t   = threadIdx.x;

    float gw[4];
    int   gp[4];

    if (t < 128) {
        const int e = t;
        const int l = (e >> 2) & 3;
        const float2 offv = *(const float2*)&off_buf[(size_t)bid * 256 + 2 * e];
        const float rx = ref_pts[(size_t)(bid * 4 + l) * 2 + 0];
        const float ry = ref_pts[(size_t)(bid * 4 + l) * 2 + 1];
        const int H = ss[2 * l], W = ss[2 * l + 1];
        const int start = lsi[l];

        const float x = (rx + offv.x / (float)W) * (float)W - 0.5f;
        const float y = (ry + offv.y / (float)H) * (float)H - 0.5f;
        const float x0f = floorf(x), y0f = floorf(y);
        const float lx = x - x0f, ly = y - y0f;
        const int ix0 = (int)x0f, iy0 = (int)y0f;
        const int ix1 = ix0 + 1,  iy1 = iy0 + 1;

        const float vx0 = (ix0 >= 0 && ix0 < W) ? 1.f : 0.f;
        const float vx1 = (ix1 >= 0 && ix1 < W) ? 1.f : 0.f;
        const float vy0 = (iy0 >= 0 && iy0 < H) ? 1.f : 0.f;
        const float vy1 = (iy1 >= 0 && iy1 < H) ? 1.f : 0.f;
        const int cx0 = min(max(ix0, 0), W - 1);
        const int cx1 = min(max(ix1, 0), W - 1);
        const int cy0 = min(max(iy0, 0), H - 1);
        const int cy1 = min(max(iy1, 0), H - 1);
        const int base = bid / Lq * LenIn + start;

        gp[0] = base + cy0 * W + cx0;
        gp[1] = base + cy0 * W + cx1;
        gp[2] = base + cy1 * W + cx0;
        gp[3] = base + cy1 * W + cx1;
        gw[0] = (1.f - lx) * (1.f - ly) * vx0 * vy0;
        gw[1] = lx * (1.f - ly) * vx1 * vy0;
        gw[2] = (1.f - lx) * ly * vx0 * vy1;
        gw[3] = lx * ly * vx1 * vy1;
    } else {
        // wave 2: softmax for all 16 (br,h) groups, 4 lanes per group,
        // concurrent with the setup phase above.
        const int lt64 = t - 128;           // 0..63
        const int grp  = lt64 >> 2;         // 0..15
        const int j4   = lt64 & 3;          // lane-in-group
        const int br   = grp >> 3;
        const int h    = grp & 7;
        const float* L = (br ? logit_bot : logit_top) + (size_t)bid * 128 + h * 16 + j4 * 4;
        const float4 lg = *(const float4*)L;
        float m = fmaxf(fmaxf(lg.x, lg.y), fmaxf(lg.z, lg.w));
        m = fmaxf(m, __shfl_xor(m, 1));
        m = fmaxf(m, __shfl_xor(m, 2));
        float e0 = expf(lg.x - m), e1 = expf(lg.y - m);
        float e2 = expf(lg.z - m), e3 = expf(lg.w - m);
        float sum = e0 + e1 + e2 + e3;
        sum += __shfl_xor(sum, 1);
        sum += __shfl_xor(sum, 2);
        const float inv = 1.f / sum;
        float* dst = &sA[br][h * 16 + j4 * 4];
        dst[0] = e0 * inv; dst[1] = e1 * inv; dst[2] = e2 * inv; dst[3] = e3 * inv;
    }
    __syncthreads();

    if (t < 128) {
        const int e = t;
        const int pidx = 4 * e + (e >> 4);
#pragma unroll
        for (int br = 0; br < 2; ++br) {
            const float a = sA[br][e];
#pragma unroll
            for (int k = 0; k < 4; ++k) {
                sP[br][pidx + k] =
                    ((unsigned)f2bfbits(gw[k] * a) << 16) | (unsigned)gp[k];
            }
        }
    }
    __syncthreads();

    // ---- phase 3: gathers ----
    const int half = t / 96;
    const int u    = t - half * 96;
    const int g    = u / 6;
    const int m    = u - g * 6;
    const int br   = g & 1;
    const int h    = g >> 1;

    const unsigned* P = sP[br];
    const char* vbase = (const char*)vcomb;             // uniform SGPR base
    const unsigned tco = (unsigned)(h * 192 + br * 96 + m * 16);

    floatx2 ac0 = {0.f, 0.f}, ac1 = {0.f, 0.f};
    floatx2 ac2 = {0.f, 0.f}, ac3 = {0.f, 0.f};
    const int lp0 = half * 8;
#pragma unroll
    for (int lp = 0; lp < 8; ++lp) {
        const int ib = 65 * h + 4 * (lp0 + lp);
#pragma unroll
        for (int k = 0; k < 4; ++k) {
            const unsigned uu = P[ib + k];
            const float wv = __uint_as_float(uu & 0xffff0000u);
            const unsigned off = (uu & 0x3fffu) * 1536u + tco;  // mad24-able
            const uint4 v = *(const uint4*)(vbase + off);
            floatx2 wv2 = {wv, wv};
            floatx2 f0 = {bflo(v.x), bfhi(v.x)};
            floatx2 f1 = {bflo(v.y), bfhi(v.y)};
            floatx2 f2 = {bflo(v.z), bfhi(v.z)};
            floatx2 f3 = {bflo(v.w), bfhi(v.w)};
            ac0 += wv2 * f0;
            ac1 += wv2 * f1;
            ac2 += wv2 * f2;
            ac3 += wv2 * f3;
        }
    }

    if (half) {
        float4 p0; p0.x = ac0.x; p0.y = ac0.y; p0.z = ac1.x; p0.w = ac1.y;
        float4 p1; p1.x = ac2.x; p1.y = ac2.y; p1.z = ac3.x; p1.w = ac3.y;
        sRed[u][0] = p0;
        sRed[u][1] = p1;
    }
    __syncthreads();
    if (!half) {
        const float4 p0 = sRed[u][0];
        const float4 p1 = sRed[u][1];
        uint4 o;
        o.x = pack2(ac0.x + p0.x, ac0.y + p0.y);
        o.y = pack2(ac1.x + p0.z, ac1.y + p0.w);
        o.z = pack2(ac2.x + p1.x, ac2.y + p1.y);
        o.w = pack2(ac3.x + p1.z, ac3.y + p1.w);
        __hip_bfloat16* dst = br ? core_bot : core_top;
        *(uint4*)&dst[(size_t)bid * DM + h * HD + m * 8] = o;
    }
}

// =====================================================================
// Host launcher — prep(q/f/weights) + GEMM1 + sampler + GEMM2.
// =====================================================================
extern "C" void kernel_launch(void* const* d_in, const int* in_sizes, int n_in,
                              void* d_out, int out_size, void* d_ws, size_t ws_size,
                              hipStream_t stream) {
    const float* query   = (const float*)d_in[0];
    const float* refpts  = (const float*)d_in[1];
    const float* flat    = (const float*)d_in[2];
    const int*   ss      = (const int*)d_in[3];
    const int*   lsi     = (const int*)d_in[4];
    const float* W_off   = (const float*)d_in[5];
    const float* b_off   = (const float*)d_in[6];
    const float* W_attn  = (const float*)d_in[7];
    const float* b_attn  = (const float*)d_in[8];
    const float* W_val   = (const float*)d_in[9];
    const float* b_val   = (const float*)d_in[10];
    const float* W_out   = (const float*)d_in[11];
    const float* b_out   = (const float*)d_in[12];
    const float* W_attn_zd = (const float*)d_in[13];
    const float* b_attn_zd = (const float*)d_in[14];
    const float* W_val_zd  = (const float*)d_in[15];
    const float* b_val_zd  = (const float*)d_in[16];
    const float* W_out_zd  = (const float*)d_in[17];
    const float* b_out_zd  = (const float*)d_in[18];

    const int Lq    = in_sizes[0] / (2 * DM);   // 5440
    const int LenIn = in_sizes[2] / (2 * DM);   // 5440
    const int M  = 2 * Lq;      // 10880
    const int Mv = 2 * LenIn;   // 10880

    float* out = (float*)d_out;

    // ---- workspace layout ----
    float* ws      = (float*)d_ws;
    float* off_buf = ws;                               // M*256 f32
    float* lt      = off_buf + (size_t)M * 256;        // M*128 f32
    float* lb      = lt + (size_t)M * 128;             // M*128 f32
    __hip_bfloat16* q_bf  = (__hip_bfloat16*)(lb + (size_t)M * 128); // M*384
    __hip_bfloat16* f_bf  = q_bf + (size_t)M * 384;    // Mv*384
    __hip_bfloat16* vcomb = f_bf + (size_t)Mv * 384;   // Mv*768 combined
    __hip_bfloat16* ct    = vcomb + (size_t)Mv * 768;  // M*384
    __hip_bfloat16* cb    = ct + (size_t)M * 384;      // M*384
    __hip_bfloat16* wtb   = cb + (size_t)M * 384;      // transposed weights

    // ---- prep: activations + weight transposes ----
    PrepParams pp;
    pp.q = query; pp.f = flat;
    pp.q_bf = q_bf; pp.f_bf = f_bf;
    const float* srcs[7] = {W_attn, W_attn_zd, W_val, W_val_zd, W_out, W_out_zd, W_off};
    const int Ks[7] = {256, 384, 256, 384, 384, 384, 256};
    const int Ns[7] = {128, 128, 384, 384, 256, 128, 256};
    __hip_bfloat16* dsts[7];
    int off = 0;
    for (int i = 0; i < 7; ++i) {
        pp.wsrc[i] = srcs[i]; pp.K[i] = Ks[i]; pp.N[i] = Ns[i];
        pp.off[i] = off;
        dsts[i] = wtb + off;
        pp.wdst[i] = dsts[i];
        off += Ks[i] * Ns[i];
    }
    pp.off[7] = off;
    pp.nQ4 = M * DM / 4;
    pp.nF4 = Mv * DM / 4;
    pp.total = pp.nQ4 + pp.nF4 + off;

    const dim3 blk(256);
    const int mg = M / 64;   // 170

    prep_kernel<<<dim3((pp.total + 255) / 256), blk, 0, stream>>>(pp);

    // ---- MEGA-GEMM 1: off + logits + values(combined scatter)
    // 1D grid 170 x 10 (128-wide y-tiles), XCD-grouped.
    {
        SegParams p;
        p.seg[0] = { q_bf, DM, dsts[6], 256, b_off,     off_buf, 256, 256, 0 }; // y0-1
        p.seg[1] = { q_bf, DM, dsts[0], 256, b_attn,    lt,      128, 256, 0 }; // y2
        p.seg[2] = { q_bf, DM, dsts[1], 384, b_attn_zd, lb,      128, 384, 0 }; // y3
        p.seg[3] = { f_bf, DM, dsts[2], 256, b_val,     vcomb,   0,   256, 2 }; // y4-6
        p.seg[4] = { f_bf, DM, dsts[3], 384, b_val_zd,  vcomb,   0,   384, 3 }; // y7-9
        p.ystart[0] = 0; p.ystart[1] = 2; p.ystart[2] = 3;
        p.ystart[3] = 4; p.ystart[4] = 7;
        p.nseg = 5; p.ny = 10;
        gemm_seg_kernel<<<dim3(mg * 10), blk, 0, stream>>>(p);
    }

    // ---- sampler: 1 query per 192-thread block, batch-interleaved ----
    sampler_kernel<<<dim3(M), dim3(192), 0, stream>>>(
        off_buf, lt, lb, refpts, ss, lsi, vcomb, ct, cb, Lq, LenIn);

    // ---- MEGA-GEMM 2: output projections, 1D grid 170 x 3, XCD-grouped ----
    {
        SegParams p;
        p.seg[0] = { ct, DM, dsts[4], 384, b_out,    out,      DM, 384, 0 }; // y0-1
        p.seg[1] = { cb, DM, dsts[5], 384, b_out_zd, out + U2, DM, 384, 0 }; // y2
        p.ystart[0] = 0; p.ystart[1] = 2;
        p.nseg = 2; p.ny = 3;
        gemm_seg_kernel<<<dim3(mg * 3), blk, 0, stream>>>(p);
    }
}

// Round 8
// 212.971 us; speedup vs baseline: 1.0120x; 1.0120x over previous
//
#include <hip/hip_runtime.h>
#include <hip/hip_bf16.h>
#include <math.h>

// Problem constants: N=2, D=384, 2U=256, nH=8, hd=48, nL=4, nP=4
#define DM   384
#define U2   256
#define HD   48

typedef __attribute__((ext_vector_type(8))) short short8;   // 8 bf16 = 4 VGPR
typedef __attribute__((ext_vector_type(4))) float floatx4;  // MFMA acc
typedef __attribute__((ext_vector_type(2))) float floatx2;  // pk_fma pair

static __device__ __forceinline__ unsigned short f2bfbits(float f) {
    __hip_bfloat16 h = __float2bfloat16(f);
    return *reinterpret_cast<unsigned short*>(&h);
}
static __device__ __forceinline__ unsigned pack2(float x, float y) {
    return (unsigned)f2bfbits(x) | ((unsigned)f2bfbits(y) << 16);
}
static __device__ __forceinline__ float bflo(unsigned u) { return __uint_as_float(u << 16); }
static __device__ __forceinline__ float bfhi(unsigned u) { return __uint_as_float(u & 0xffff0000u); }

// =====================================================================
// Prep (R4-proven): query->bf16, flat->bf16 (vectorized) + 7 weight
// transposes. Separate bf16 cast pass AMORTIZES the A re-reads in
// GEMM1 (8-12x per matrix) — fusing the cast into GEMM1 regressed (R5).
// =====================================================================
struct PrepParams {
    const float* q; const float* f;
    __hip_bfloat16 *q_bf, *f_bf;
    const float* wsrc[7]; __hip_bfloat16* wdst[7];
    int K[7], N[7], off[8];
    int nQ4, nF4, total;
};
__global__ __launch_bounds__(256) void prep_kernel(PrepParams d) {
    const int idx = blockIdx.x * 256 + threadIdx.x;
    if (idx >= d.total) return;
    if (idx < d.nQ4) {
        const int i4 = idx * 4;
        const float4 v = *(const float4*)&d.q[i4];
        uint2 pk; pk.x = pack2(v.x, v.y); pk.y = pack2(v.z, v.w);
        *(uint2*)&d.q_bf[i4] = pk;
        return;
    }
    if (idx < d.nQ4 + d.nF4) {
        const int i4 = (idx - d.nQ4) * 4;
        const float4 v = *(const float4*)&d.f[i4];
        uint2 pk; pk.x = pack2(v.x, v.y); pk.y = pack2(v.z, v.w);
        *(uint2*)&d.f_bf[i4] = pk;
        return;
    }
    const int iw = idx - d.nQ4 - d.nF4;
    int s = 0;
#pragma unroll
    for (int i = 1; i < 7; ++i) if (iw >= d.off[i]) s = i;
    const int r = iw - d.off[s];
    const int k = r / d.N[s], n = r - k * d.N[s];
    d.wdst[s][(size_t)n * d.K[s] + k] = __float2bfloat16(d.wsrc[s][r]);
}

// =====================================================================
// Multi-segment MFMA GEMM — proven R0 structure: 64x64 tile / BK=32,
// 2x5KB LDS (high occupancy), register prefetch, bf16 A.
// 1D grid + bijective chunked XCD remap (R6-proven, -6us): all ny
// y-blocks sharing one A-panel (same bx) run on the SAME XCD -> A
// re-reads hit that XCD's L2 instead of migrating across all 8 L2s.
// (R7 note: 64x128 N-widening regressed — it perturbs vcomb L2
// residency and slows the downstream sampler by ~3us.)
// omode: 0 = f32 out; 1 = bf16 out; 2/3 = bf16 scatter into combined
// value layout (top/bot): idx = row*768 + (col/48)*96 + (omode==3)*48 + col%48
// =====================================================================
struct Seg {
    const __hip_bfloat16* A; int lda;
    const __hip_bfloat16* Bt; int ldbt;
    const float* bias; void* C; int ldc; int K; int omode;
};
struct SegParams { Seg seg[5]; int ystart[5]; int nseg; int ny; };

__global__ __launch_bounds__(256) void gemm_seg_kernel(SegParams p) {
    __shared__ __hip_bfloat16 As[64 * 40];
    __shared__ __hip_bfloat16 Bs[64 * 40];

    // ---- XCD y-grouping remap (bijective chunked, m204 form) ----
    // XCD c = id%8 owns work-items i in [c*q8+min(c,r8), +count_c),
    // walked y-fastest -> same-bx blocks co-locate on one XCD.
    const int nb = gridDim.x;
    const int q8 = nb >> 3, r8 = nb & 7;
    const int c  = blockIdx.x & 7;
    const int i  = c * q8 + min(c, r8) + (blockIdx.x >> 3);
    const int bxi = i / p.ny;
    const int yb  = i - bxi * p.ny;

    int s = 0;
#pragma unroll
    for (int k = 1; k < 5; ++k) if (k < p.nseg && yb >= p.ystart[k]) s = k;
    Seg sg;
    switch (s) {
        case 0: sg = p.seg[0]; break;
        case 1: sg = p.seg[1]; break;
        case 2: sg = p.seg[2]; break;
        case 3: sg = p.seg[3]; break;
        default: sg = p.seg[4]; break;
    }
    const int by = yb - p.ystart[s];

    const int t    = threadIdx.x;
    const int bm   = bxi * 64;
    const int bn   = by * 64;
    const int w    = t >> 6, lane = t & 63;
    const int wm   = (w >> 1) * 32, wn = (w & 1) * 32;
    const int quad = lane >> 4, lm = lane & 15;

    const int r0 = t >> 2, kc = (t & 3) * 8;

    const __hip_bfloat16* Ap = sg.A  + (size_t)(bm + r0) * sg.lda  + kc;
    const __hip_bfloat16* Bp = sg.Bt + (size_t)(bn + r0) * sg.ldbt + kc;

    short8 abf = *(const short8*)Ap;
    short8 bbf = *(const short8*)Bp;

    floatx4 acc[2][2] = {};

    for (int k0 = 0; k0 < sg.K; k0 += 32) {
        *(short8*)&As[r0 * 40 + kc] = abf;
        *(short8*)&Bs[r0 * 40 + kc] = bbf;
        __syncthreads();

        const int kn = k0 + 32;
        if (kn < sg.K) {
            abf = *(const short8*)(Ap + kn);
            bbf = *(const short8*)(Bp + kn);
        }

        short8 af[2], bf[2];
#pragma unroll
        for (int ii = 0; ii < 2; ++ii)
            af[ii] = *(const short8*)&As[(wm + ii * 16 + lm) * 40 + quad * 8];
#pragma unroll
        for (int j = 0; j < 2; ++j)
            bf[j] = *(const short8*)&Bs[(wn + j * 16 + lm) * 40 + quad * 8];
#pragma unroll
        for (int ii = 0; ii < 2; ++ii)
#pragma unroll
            for (int j = 0; j < 2; ++j)
                acc[ii][j] = __builtin_amdgcn_mfma_f32_16x16x32_bf16(
                    af[ii], bf[j], acc[ii][j], 0, 0, 0);
        __syncthreads();
    }

#pragma unroll
    for (int ii = 0; ii < 2; ++ii)
#pragma unroll
        for (int reg = 0; reg < 4; ++reg) {
            const int row = bm + wm + ii * 16 + quad * 4 + reg;
#pragma unroll
            for (int j = 0; j < 2; ++j) {
                const int col = bn + wn + j * 16 + lm;
                const float v = acc[ii][j][reg] + sg.bias[col];
                if (sg.omode == 0) {
                    ((float*)sg.C)[(size_t)row * sg.ldc + col] = v;
                } else if (sg.omode == 1) {
                    ((__hip_bfloat16*)sg.C)[(size_t)row * sg.ldc + col] = __float2bfloat16(v);
                } else {
                    const int h = col / 48;
                    const size_t idx = (size_t)row * 768 + h * 96 +
                                       ((sg.omode == 3) ? 48 : 0) + (col - h * 48);
                    ((__hip_bfloat16*)sg.C)[idx] = __float2bfloat16(v);
                }
            }
        }
}

// =====================================================================
// Fused sampler v12 (exact R2 form — measured 56.8-57.4 us, 739K bank
// conflicts; at its ~2.1GB/dispatch L2-BW roofline, ~37.5 TB/s eff):
//  - batch-interleaved blockIdx mapping (XCD parity split)
//  - softmax on wave 2, concurrent with setup phase
// =====================================================================
#define SPP 524

__global__ __launch_bounds__(192) void sampler_kernel(
    const float* __restrict__ off_buf,    // (M, 256) fp32
    const float* __restrict__ logit_top,  // (M, 128)
    const float* __restrict__ logit_bot,  // (M, 128)
    const float* __restrict__ ref_pts,    // (M, 4, 2)
    const int*   __restrict__ ss,         // (4,2) [H,W]
    const int*   __restrict__ lsi,        // (4,)
    const __hip_bfloat16* __restrict__ vcomb,  // (Mv, 768) combined
    __hip_bfloat16* __restrict__ core_top,     // (M, 384) bf16
    __hip_bfloat16* __restrict__ core_bot,     // (M, 384) bf16
    int Lq, int LenIn)
{
    __shared__ float    sA[2][128];
    __shared__ unsigned sP[2][SPP];
    __shared__ float4   sRed[96][2];

    // batch-interleave: even bx -> batch 0, odd bx -> batch 1
    const int bx  = blockIdx.x;
    const int bid = (bx & 1) * Lq + (bx >> 1);
    const int t   = threadIdx.x;

    float gw[4];
    int   gp[4];

    if (t < 128) {
        const int e = t;
        const int l = (e >> 2) & 3;
        const float2 offv = *(const float2*)&off_buf[(size_t)bid * 256 + 2 * e];
        const float rx = ref_pts[(size_t)(bid * 4 + l) * 2 + 0];
        const float ry = ref_pts[(size_t)(bid * 4 + l) * 2 + 1];
        const int H = ss[2 * l], W = ss[2 * l + 1];
        const int start = lsi[l];

        const float x = (rx + offv.x / (float)W) * (float)W - 0.5f;
        const float y = (ry + offv.y / (float)H) * (float)H - 0.5f;
        const float x0f = floorf(x), y0f = floorf(y);
        const float lx = x - x0f, ly = y - y0f;
        const int ix0 = (int)x0f, iy0 = (int)y0f;
        const int ix1 = ix0 + 1,  iy1 = iy0 + 1;

        const float vx0 = (ix0 >= 0 && ix0 < W) ? 1.f : 0.f;
        const float vx1 = (ix1 >= 0 && ix1 < W) ? 1.f : 0.f;
        const float vy0 = (iy0 >= 0 && iy0 < H) ? 1.f : 0.f;
        const float vy1 = (iy1 >= 0 && iy1 < H) ? 1.f : 0.f;
        const int cx0 = min(max(ix0, 0), W - 1);
        const int cx1 = min(max(ix1, 0), W - 1);
        const int cy0 = min(max(iy0, 0), H - 1);
        const int cy1 = min(max(iy1, 0), H - 1);
        const int base = bid / Lq * LenIn + start;

        gp[0] = base + cy0 * W + cx0;
        gp[1] = base + cy0 * W + cx1;
        gp[2] = base + cy1 * W + cx0;
        gp[3] = base + cy1 * W + cx1;
        gw[0] = (1.f - lx) * (1.f - ly) * vx0 * vy0;
        gw[1] = lx * (1.f - ly) * vx1 * vy0;
        gw[2] = (1.f - lx) * ly * vx0 * vy1;
        gw[3] = lx * ly * vx1 * vy1;
    } else {
        // wave 2: softmax for all 16 (br,h) groups, 4 lanes per group,
        // concurrent with the setup phase above.
        const int lt64 = t - 128;           // 0..63
        const int grp  = lt64 >> 2;         // 0..15
        const int j4   = lt64 & 3;          // lane-in-group
        const int br   = grp >> 3;
        const int h    = grp & 7;
        const float* L = (br ? logit_bot : logit_top) + (size_t)bid * 128 + h * 16 + j4 * 4;
        const float4 lg = *(const float4*)L;
        float m = fmaxf(fmaxf(lg.x, lg.y), fmaxf(lg.z, lg.w));
        m = fmaxf(m, __shfl_xor(m, 1));
        m = fmaxf(m, __shfl_xor(m, 2));
        float e0 = expf(lg.x - m), e1 = expf(lg.y - m);
        float e2 = expf(lg.z - m), e3 = expf(lg.w - m);
        float sum = e0 + e1 + e2 + e3;
        sum += __shfl_xor(sum, 1);
        sum += __shfl_xor(sum, 2);
        const float inv = 1.f / sum;
        float* dst = &sA[br][h * 16 + j4 * 4];
        dst[0] = e0 * inv; dst[1] = e1 * inv; dst[2] = e2 * inv; dst[3] = e3 * inv;
    }
    __syncthreads();

    if (t < 128) {
        const int e = t;
        const int pidx = 4 * e + (e >> 4);
#pragma unroll
        for (int br = 0; br < 2; ++br) {
            const float a = sA[br][e];
#pragma unroll
            for (int k = 0; k < 4; ++k) {
                sP[br][pidx + k] =
                    ((unsigned)f2bfbits(gw[k] * a) << 16) | (unsigned)gp[k];
            }
        }
    }
    __syncthreads();

    // ---- phase 3: gathers ----
    const int half = t / 96;
    const int u    = t - half * 96;
    const int g    = u / 6;
    const int m    = u - g * 6;
    const int br   = g & 1;
    const int h    = g >> 1;

    const unsigned* P = sP[br];
    const char* vbase = (const char*)vcomb;             // uniform SGPR base
    const unsigned tco = (unsigned)(h * 192 + br * 96 + m * 16);

    floatx2 ac0 = {0.f, 0.f}, ac1 = {0.f, 0.f};
    floatx2 ac2 = {0.f, 0.f}, ac3 = {0.f, 0.f};
    const int lp0 = half * 8;
#pragma unroll
    for (int lp = 0; lp < 8; ++lp) {
        const int ib = 65 * h + 4 * (lp0 + lp);
#pragma unroll
        for (int k = 0; k < 4; ++k) {
            const unsigned uu = P[ib + k];
            const float wv = __uint_as_float(uu & 0xffff0000u);
            const unsigned off = (uu & 0x3fffu) * 1536u + tco;  // mad24-able
            const uint4 v = *(const uint4*)(vbase + off);
            floatx2 wv2 = {wv, wv};
            floatx2 f0 = {bflo(v.x), bfhi(v.x)};
            floatx2 f1 = {bflo(v.y), bfhi(v.y)};
            floatx2 f2 = {bflo(v.z), bfhi(v.z)};
            floatx2 f3 = {bflo(v.w), bfhi(v.w)};
            ac0 += wv2 * f0;
            ac1 += wv2 * f1;
            ac2 += wv2 * f2;
            ac3 += wv2 * f3;
        }
    }

    if (half) {
        float4 p0; p0.x = ac0.x; p0.y = ac0.y; p0.z = ac1.x; p0.w = ac1.y;
        float4 p1; p1.x = ac2.x; p1.y = ac2.y; p1.z = ac3.x; p1.w = ac3.y;
        sRed[u][0] = p0;
        sRed[u][1] = p1;
    }
    __syncthreads();
    if (!half) {
        const float4 p0 = sRed[u][0];
        const float4 p1 = sRed[u][1];
        uint4 o;
        o.x = pack2(ac0.x + p0.x, ac0.y + p0.y);
        o.y = pack2(ac1.x + p0.z, ac1.y + p0.w);
        o.z = pack2(ac2.x + p1.x, ac2.y + p1.y);
        o.w = pack2(ac3.x + p1.z, ac3.y + p1.w);
        __hip_bfloat16* dst = br ? core_bot : core_top;
        *(uint4*)&dst[(size_t)bid * DM + h * HD + m * 8] = o;
    }
}

// =====================================================================
// Host launcher — prep(q/f/weights) + GEMM1 + sampler + GEMM2.
// =====================================================================
extern "C" void kernel_launch(void* const* d_in, const int* in_sizes, int n_in,
                              void* d_out, int out_size, void* d_ws, size_t ws_size,
                              hipStream_t stream) {
    const float* query   = (const float*)d_in[0];
    const float* refpts  = (const float*)d_in[1];
    const float* flat    = (const float*)d_in[2];
    const int*   ss      = (const int*)d_in[3];
    const int*   lsi     = (const int*)d_in[4];
    const float* W_off   = (const float*)d_in[5];
    const float* b_off   = (const float*)d_in[6];
    const float* W_attn  = (const float*)d_in[7];
    const float* b_attn  = (const float*)d_in[8];
    const float* W_val   = (const float*)d_in[9];
    const float* b_val   = (const float*)d_in[10];
    const float* W_out   = (const float*)d_in[11];
    const float* b_out   = (const float*)d_in[12];
    const float* W_attn_zd = (const float*)d_in[13];
    const float* b_attn_zd = (const float*)d_in[14];
    const float* W_val_zd  = (const float*)d_in[15];
    const float* b_val_zd  = (const float*)d_in[16];
    const float* W_out_zd  = (const float*)d_in[17];
    const float* b_out_zd  = (const float*)d_in[18];

    const int Lq    = in_sizes[0] / (2 * DM);   // 5440
    const int LenIn = in_sizes[2] / (2 * DM);   // 5440
    const int M  = 2 * Lq;      // 10880
    const int Mv = 2 * LenIn;   // 10880

    float* out = (float*)d_out;

    // ---- workspace layout ----
    float* ws      = (float*)d_ws;
    float* off_buf = ws;                               // M*256 f32
    float* lt      = off_buf + (size_t)M * 256;        // M*128 f32
    float* lb      = lt + (size_t)M * 128;             // M*128 f32
    __hip_bfloat16* q_bf  = (__hip_bfloat16*)(lb + (size_t)M * 128); // M*384
    __hip_bfloat16* f_bf  = q_bf + (size_t)M * 384;    // Mv*384
    __hip_bfloat16* vcomb = f_bf + (size_t)Mv * 384;   // Mv*768 combined
    __hip_bfloat16* ct    = vcomb + (size_t)Mv * 768;  // M*384
    __hip_bfloat16* cb    = ct + (size_t)M * 384;      // M*384
    __hip_bfloat16* wtb   = cb + (size_t)M * 384;      // transposed weights

    // ---- prep: activations + weight transposes ----
    PrepParams pp;
    pp.q = query; pp.f = flat;
    pp.q_bf = q_bf; pp.f_bf = f_bf;
    const float* srcs[7] = {W_attn, W_attn_zd, W_val, W_val_zd, W_out, W_out_zd, W_off};
    const int Ks[7] = {256, 384, 256, 384, 384, 384, 256};
    const int Ns[7] = {128, 128, 384, 384, 256, 128, 256};
    __hip_bfloat16* dsts[7];
    int off = 0;
    for (int i = 0; i < 7; ++i) {
        pp.wsrc[i] = srcs[i]; pp.K[i] = Ks[i]; pp.N[i] = Ns[i];
        pp.off[i] = off;
        dsts[i] = wtb + off;
        pp.wdst[i] = dsts[i];
        off += Ks[i] * Ns[i];
    }
    pp.off[7] = off;
    pp.nQ4 = M * DM / 4;
    pp.nF4 = Mv * DM / 4;
    pp.total = pp.nQ4 + pp.nF4 + off;

    const dim3 blk(256);
    const int mg = M / 64;   // 170

    prep_kernel<<<dim3((pp.total + 255) / 256), blk, 0, stream>>>(pp);

    // ---- MEGA-GEMM 1: off + logits + values(combined scatter), 1D grid
    // 170x20 work-items, XCD-grouped so same-bx blocks share one L2.
    {
        SegParams p;
        p.seg[0] = { q_bf, DM, dsts[6], 256, b_off,     off_buf, 256, 256, 0 }; // y0-3
        p.seg[1] = { q_bf, DM, dsts[0], 256, b_attn,    lt,      128, 256, 0 }; // y4-5
        p.seg[2] = { q_bf, DM, dsts[1], 384, b_attn_zd, lb,      128, 384, 0 }; // y6-7
        p.seg[3] = { f_bf, DM, dsts[2], 256, b_val,     vcomb,   0,   256, 2 }; // y8-13
        p.seg[4] = { f_bf, DM, dsts[3], 384, b_val_zd,  vcomb,   0,   384, 3 }; // y14-19
        p.ystart[0] = 0; p.ystart[1] = 4; p.ystart[2] = 6;
        p.ystart[3] = 8; p.ystart[4] = 14;
        p.nseg = 5; p.ny = 20;
        gemm_seg_kernel<<<dim3(mg * 20), blk, 0, stream>>>(p);
    }

    // ---- sampler: 1 query per 192-thread block, batch-interleaved ----
    sampler_kernel<<<dim3(M), dim3(192), 0, stream>>>(
        off_buf, lt, lb, refpts, ss, lsi, vcomb, ct, cb, Lq, LenIn);

    // ---- MEGA-GEMM 2: output projections, 1D grid 170x6, XCD-grouped ----
    {
        SegParams p;
        p.seg[0] = { ct, DM, dsts[4], 384, b_out,    out,      DM, 384, 0 }; // y0-3
        p.seg[1] = { cb, DM, dsts[5], 384, b_out_zd, out + U2, DM, 384, 0 }; // y2
        p.ystart[0] = 0; p.ystart[1] = 4;
        p.nseg = 2; p.ny = 6;
        gemm_seg_kernel<<<dim3(mg * 6), blk, 0, stream>>>(p);
    }
}